// Round 7
// baseline (656.072 us; speedup 1.0000x reference)
//
#include <hip/hip_runtime.h>
#include <hip/hip_fp16.h>

// LMKAN_2D: out(O=256,B=4096) = relu(W(256x128)@x(128x4096) + bias_l)
//           + w_lm * sum_p bilinear4(fp[i,j,:,p])
// K1 transpose: fp[i][j][o][p] f32 -> fpt[i][j][p][o] f16 (132 MiB). Both
//    global sides 1KB/wave contiguous; LDS XOR-swizzled. Also zeroes barrier ctrl.
// K2 gather (persistent, XCD-phased, GRID-BARRIER-aligned): 512 blocks x 256
//    thr, 2 blocks/CU co-resident. XCD x = bid&7 owns p in [8x,8x+8), one p
//    per phase; the per-p table slab (2.1 MiB) stays resident in that XCD's
//    4 MiB L2 for the whole phase -> ~3.9x reuse served by L2 instead of
//    HBM/L3 (R6 measured FETCH=483MB=zero reuse WITHOUT alignment; the
//    barrier enforces the equilibrium drift destroyed). Barrier is
//    generation-based with TIMEOUT: pure timing aid, correctness never
//    depends on it, no deadlock possible.
// K3 linear: 128-block GEMM computes relu(Wx+b), folds 8 partials, writes out.

#define NB 4096
#define ND 128
#define NO 256
#define NP 64
#define NG 65
#define PANEL 16384  // 256*64 elements per (i,j) panel
#define FPT_ELEMS ((size_t)NG * NG * PANEL)
#define FPT_BYTES (FPT_ELEMS * 2)                  // 138,444,800 B
#define PART_FLOATS ((size_t)8 * NB * NO)          // 32 MiB
#define NBLK 512

typedef float f32x4 __attribute__((ext_vector_type(4)));
union Pack8 { __half h[8]; uint4 v; };

__device__ __forceinline__ int bsearch65(const float* B, float v) {
  int lo = 0, hi = 65;
  while (lo < hi) {
    int m = (lo + hi) >> 1;
    if (B[m] <= v) lo = m + 1; else hi = m;
  }
  int i = lo - 1;
  return i < 0 ? 0 : (i > 63 ? 63 : i);
}

__device__ __forceinline__ void borders_init(float* borders, int t) {
  if (t < 65) {
    float pk = fminf(fmaxf((float)t * (1.0f / 64.0f), 0.0078125f), 0.9921875f);
    borders[t] = 1.41421356237309515f * erfinvf(2.0f * pk - 1.0f);
  }
}

// Timing-only grid barrier: generation counter + bounded spin (no deadlock).
__device__ __forceinline__ void grid_barrier(unsigned* cnt, unsigned* gen) {
  __syncthreads();
  if (threadIdx.x == 0) {
    unsigned g = __hip_atomic_load(gen, __ATOMIC_ACQUIRE, __HIP_MEMORY_SCOPE_AGENT);
    unsigned a = __hip_atomic_fetch_add(cnt, 1u, __ATOMIC_ACQ_REL,
                                        __HIP_MEMORY_SCOPE_AGENT) + 1u;
    if (a == NBLK) {
      __hip_atomic_store(cnt, 0u, __ATOMIC_RELAXED, __HIP_MEMORY_SCOPE_AGENT);
      __hip_atomic_fetch_add(gen, 1u, __ATOMIC_ACQ_REL, __HIP_MEMORY_SCOPE_AGENT);
    } else {
      for (int it = 0; it < 256; ++it) {   // bounded: timing aid only
        if (__hip_atomic_load(gen, __ATOMIC_ACQUIRE,
                              __HIP_MEMORY_SCOPE_AGENT) != g) break;
        __builtin_amdgcn_s_sleep(4);
      }
    }
  }
  __syncthreads();
}

// ---- K1: transpose fp[panel][o][p] f32 -> fpt[panel][p][o] f16 ----
__global__ __launch_bounds__(256) void lmkan_transpose3(
    const float* __restrict__ src, __half* __restrict__ dst,
    unsigned* __restrict__ ctrl) {
  const int panel = blockIdx.x;
  const int t = threadIdx.x;
  __shared__ __half lds[256 * 72];   // [o][72], p XOR-swizzled inside row

  if (panel == 0 && t < 2) ctrl[t] = 0u;   // reset barrier state every replay

  const f32x4* s4 = reinterpret_cast<const f32x4*>(src + (size_t)panel * PANEL);
#pragma unroll
  for (int k = 0; k < 16; ++k) {
    int idx4 = t + 256 * k;          // 1KB contiguous per wave
    f32x4 v = __builtin_nontemporal_load(&s4[idx4]);  // read-once
    int o = idx4 >> 4;
    int p0 = (idx4 & 15) * 4;
    int p0s = p0 ^ (((o >> 3) & 15) << 2);
    union { __half2 h2[2]; uint2 u; } pk;
    pk.h2[0] = __floats2half2_rn(v[0], v[1]);
    pk.h2[1] = __floats2half2_rn(v[2], v[3]);
    *reinterpret_cast<uint2*>(&lds[o * 72 + p0s]) = pk.u;
  }
  __syncthreads();

  const int l = t & 63, w = t >> 6;
  const int o0 = (l & 31) * 8;
  const int swz = (l & 15) << 2;
#pragma unroll
  for (int ss = 0; ss < 8; ++ss) {
    int p = ss * 8 + w * 2 + (l >> 5);
    int prow = ((p & ~3) ^ swz) + (p & 3);
    Pack8 pk;
#pragma unroll
    for (int r = 0; r < 8; ++r) pk.h[r] = lds[(o0 + r) * 72 + prow];
    *reinterpret_cast<uint4*>(dst + ((size_t)panel * 64 + p) * NO + o0) = pk.v;
  }
}

__device__ __forceinline__ void fma4h(float acc[4], float w, uint2 v) {
  __half2 h0 = *reinterpret_cast<__half2*>(&v.x);
  __half2 h1 = *reinterpret_cast<__half2*>(&v.y);
  float2 f0 = __half22float2(h0);
  float2 f1 = __half22float2(h1);
  acc[0] = fmaf(w, f0.x, acc[0]);
  acc[1] = fmaf(w, f0.y, acc[1]);
  acc[2] = fmaf(w, f1.x, acc[2]);
  acc[3] = fmaf(w, f1.y, acc[3]);
}

// ---- K2: persistent XCD-phased gather with aligned phases -> partials ----
__global__ __launch_bounds__(256, 2) void lmkan_gather7(
    const float* __restrict__ x, const float* __restrict__ scale,
    const float* __restrict__ biasp, const __half* __restrict__ fpt,
    float* __restrict__ part, unsigned* __restrict__ ctrl) {
  const int xcd = blockIdx.x & 7;    // owns p in [8*xcd, 8*xcd+8)
  const int m   = blockIdx.x >> 3;   // 0..63: b-range [64m, 64m+64)
  const int t = threadIdx.x;         // 0..255
  const int w = t >> 6;              // wave 0..3: b-locals [16w, 16w+16)
  const int l = t & 63;              // lane owns o = 4l..4l+3
  const int loff = 4 * l;

  __shared__ float borders[66];
  __shared__ int jb[64];             // element base of (panel(i,j), p, o=0)
  __shared__ float4 w4[64];          // {w00, w01, w10, w11}

  borders_init(borders, t);
  __syncthreads();

  float acc[16][4] = {};

  for (int ph = 0; ph < 8; ++ph) {
    const int p = 8 * xcd + ph;
    if (t < 64) {
      const int b = m * 64 + t;
      float x1 = x[(size_t)(2 * p) * NB + b]     * scale[2 * p]     + biasp[2 * p];
      float x2 = x[(size_t)(2 * p + 1) * NB + b] * scale[2 * p + 1] + biasp[2 * p + 1];
      const float lo = borders[0];
      const float hi = borders[64] - 1e-6f;
      x1 = fminf(fmaxf(x1, lo), hi);
      x2 = fminf(fmaxf(x2, lo), hi);
      int i = bsearch65(borders, x1);
      int j = bsearch65(borders, x2);
      float t1 = (x1 - borders[i]) / (borders[i + 1] - borders[i]);
      float t2 = (x2 - borders[j]) / (borders[j + 1] - borders[j]);
      jb[t] = ((i * NG + j) * 64 + p) * NO;
      w4[t] = make_float4((1.0f - t1) * (1.0f - t2),  // (i,   j)  : +0
                          (1.0f - t1) * t2,           // (i,   j+1): +PANEL
                          t1 * (1.0f - t2),           // (i+1, j)  : +65*PANEL
                          t1 * t2);                   // (i+1, j+1): +66*PANEL
    }
    __syncthreads();
#pragma unroll
    for (int bb = 0; bb < 16; ++bb) {
      const int bl = w * 16 + bb;
      const float4 wv = w4[bl];
      const __half* q = fpt + jb[bl] + loff;
      uint2 vA = *reinterpret_cast<const uint2*>(q);
      uint2 vB = *reinterpret_cast<const uint2*>(q + PANEL);
      uint2 vC = *reinterpret_cast<const uint2*>(q + 65 * PANEL);
      uint2 vD = *reinterpret_cast<const uint2*>(q + 66 * PANEL);
      fma4h(acc[bb], wv.x, vA);
      fma4h(acc[bb], wv.y, vB);
      fma4h(acc[bb], wv.z, vC);
      fma4h(acc[bb], wv.w, vD);
    }
    if (ph < 7) grid_barrier(&ctrl[0], &ctrl[1]);  // keep XCD on one slab
  }

  // write partials: part[xcd][b][o], per-XCD contiguous 4 MiB
#pragma unroll
  for (int bb = 0; bb < 16; ++bb) {
    const int b = m * 64 + w * 16 + bb;
    *reinterpret_cast<float4*>(&part[((size_t)xcd * NB + b) * NO + loff]) =
        make_float4(acc[bb][0], acc[bb][1], acc[bb][2], acc[bb][3]);
  }
}

// ---- K3: out = relu(W@x + bias) + wlm * sum_k part ----
__global__ __launch_bounds__(256) void lmkan_linear2(
    const float* __restrict__ x, const float* __restrict__ W,
    const float* __restrict__ bias_l, const int* __restrict__ relu_p,
    const float* __restrict__ wlm_p, const float* __restrict__ part,
    float* __restrict__ out) {
  const int b0 = blockIdx.x * 32;
  const int t = threadIdx.x;          // = output row o
  __shared__ __align__(16) float xs[32 * 132];

#pragma unroll
  for (int k = 0; k < 16; ++k) {
    int idx = t + 256 * k;
    int d = idx >> 5, bb = idx & 31;
    xs[bb * 132 + d] = x[(size_t)d * NB + b0 + bb];
  }
  __syncthreads();

  float acc[32];
#pragma unroll
  for (int bb = 0; bb < 32; ++bb) acc[bb] = 0.0f;

  const float4* W4 = reinterpret_cast<const float4*>(W + (size_t)t * ND);
#pragma unroll 8
  for (int d4 = 0; d4 < 32; ++d4) {
    float4 wv = W4[d4];
#pragma unroll
    for (int bb = 0; bb < 32; ++bb) {
      float4 xv = *reinterpret_cast<const float4*>(&xs[bb * 132 + d4 * 4]);
      acc[bb] = fmaf(wv.x, xv.x, acc[bb]);
      acc[bb] = fmaf(wv.y, xv.y, acc[bb]);
      acc[bb] = fmaf(wv.z, xv.z, acc[bb]);
      acc[bb] = fmaf(wv.w, xv.w, acc[bb]);
    }
  }

  const float bias = bias_l[t];
  const int rl = relu_p[0];
  const float wlm = wlm_p[0];
  float* orow = out + (size_t)t * NB + b0;
#pragma unroll 4
  for (int bb = 0; bb < 32; ++bb) {
    float lmsum = 0.0f;
    const float* pr = part + (size_t)(b0 + bb) * NO + t;  // lanes coalesced
#pragma unroll
    for (int k = 0; k < 8; ++k) lmsum += pr[(size_t)k * NB * NO];
    float v = acc[bb] + bias;
    if (rl) v = fmaxf(v, 0.0f);
    orow[bb] = v + wlm * lmsum;
  }
}

// ---- Fallback: direct fp32 gather, fused linear (exact, slow) ----
__global__ __launch_bounds__(64) void lmkan_gather_direct(
    const float* __restrict__ x, const float* __restrict__ scale,
    const float* __restrict__ biasp, const float* __restrict__ W,
    const float* __restrict__ bias_l, const float* __restrict__ wlm_p,
    const int* __restrict__ relu_p, const float* __restrict__ fp,
    float* __restrict__ out) {
  const int b = blockIdx.x;
  const int t = threadIdx.x;

  __shared__ float borders[66];
  __shared__ __align__(16) float xcol[ND];
  __shared__ int pbase[NP];
  __shared__ float4 pw[NP];

  for (int k = t; k < 65; k += 64) {
    float pk = fminf(fmaxf((float)k * (1.0f / 64.0f), 0.0078125f), 0.9921875f);
    borders[k] = 1.41421356237309515f * erfinvf(2.0f * pk - 1.0f);
  }
  xcol[t]      = x[(size_t)t * NB + b];
  xcol[t + 64] = x[(size_t)(t + 64) * NB + b];
  __syncthreads();

  {
    const int p = t;
    float x1 = xcol[2 * p]     * scale[2 * p]     + biasp[2 * p];
    float x2 = xcol[2 * p + 1] * scale[2 * p + 1] + biasp[2 * p + 1];
    const float lo = borders[0];
    const float hi = borders[64] - 1e-6f;
    x1 = fminf(fmaxf(x1, lo), hi);
    x2 = fminf(fmaxf(x2, lo), hi);
    int i = bsearch65(borders, x1);
    int j = bsearch65(borders, x2);
    float t1 = (x1 - borders[i]) / (borders[i + 1] - borders[i]);
    float t2 = (x2 - borders[j]) / (borders[j + 1] - borders[j]);
    pbase[p] = i * NG + j;
    pw[p] = make_float4((1.0f - t1) * (1.0f - t2), t1 * (1.0f - t2),
                        (1.0f - t1) * t2, t1 * t2);
  }
  __syncthreads();

  float acc[4] = {0, 0, 0, 0};
  for (int p = 0; p < NP; ++p) {
    int base = pbase[p];
    float4 wv = pw[p];
#pragma unroll
    for (int k = 0; k < 4; ++k) {
      size_t r = ((size_t)base * NO + (4 * t + k)) * NP + p;
      acc[k] += wv.x * fp[r] + wv.y * fp[r + 65 * PANEL] +
                wv.z * fp[r + PANEL] + wv.w * fp[r + 66 * PANEL];
    }
  }

  const float wlm = wlm_p[0];
  const int rl = relu_p[0];
  const float4* xc4 = reinterpret_cast<const float4*>(xcol);
#pragma unroll
  for (int k = 0; k < 4; ++k) {
    const int o = 4 * t + k;
    const float4* wr = reinterpret_cast<const float4*>(W + (size_t)o * ND);
    float s = 0.0f;
#pragma unroll 8
    for (int d4 = 0; d4 < ND / 4; ++d4) {
      float4 wv = wr[d4];
      float4 xv = xc4[d4];
      s = fmaf(wv.x, xv.x, s);
      s = fmaf(wv.y, xv.y, s);
      s = fmaf(wv.z, xv.z, s);
      s = fmaf(wv.w, xv.w, s);
    }
    s += bias_l[o];
    if (rl) s = fmaxf(s, 0.0f);
    out[(size_t)o * NB + b] = s + wlm * acc[k];
  }
}

extern "C" void kernel_launch(void* const* d_in, const int* in_sizes, int n_in,
                              void* d_out, int out_size, void* d_ws, size_t ws_size,
                              hipStream_t stream) {
  const float* x     = reinterpret_cast<const float*>(d_in[0]);
  const float* wlm   = reinterpret_cast<const float*>(d_in[1]);
  const int*   relu  = reinterpret_cast<const int*>(d_in[2]);
  const float* fp    = reinterpret_cast<const float*>(d_in[3]);
  const float* scale = reinterpret_cast<const float*>(d_in[4]);
  const float* biasp = reinterpret_cast<const float*>(d_in[5]);
  const float* W     = reinterpret_cast<const float*>(d_in[6]);
  const float* bl    = reinterpret_cast<const float*>(d_in[7]);
  float* out = reinterpret_cast<float*>(d_out);

  const size_t need = FPT_BYTES + PART_FLOATS * sizeof(float) + 64;
  if (ws_size >= need) {
    char* base = reinterpret_cast<char*>(d_ws);
    __half* fpt = reinterpret_cast<__half*>(base);
    float* part = reinterpret_cast<float*>(base + FPT_BYTES);
    unsigned* ctrl = reinterpret_cast<unsigned*>(
        base + FPT_BYTES + PART_FLOATS * sizeof(float));
    lmkan_transpose3<<<NG * NG, 256, 0, stream>>>(fp, fpt, ctrl);
    lmkan_gather7<<<NBLK, 256, 0, stream>>>(x, scale, biasp, fpt, part, ctrl);
    lmkan_linear2<<<NB / 32, 256, 0, stream>>>(x, W, bl, relu, wlm, part, out);
  } else {
    lmkan_gather_direct<<<NB, 64, 0, stream>>>(x, scale, biasp, W, bl, wlm, relu, fp, out);
  }
}

// Round 8
// 304.742 us; speedup vs baseline: 2.1529x; 2.1529x over previous
//
#include <hip/hip_runtime.h>
#include <hip/hip_fp16.h>

// LMKAN_2D: out(O=256,B=4096) = relu(W(256x128)@x(128x4096) + bias_l)
//           + w_lm * sum_p bilinear4(fp[i,j,:,p])
// K1 transpose: fp[i][j][o][p] f32 -> fpt[i][j][p][o] f16 (132 MiB). Both
//    global sides 1KB/wave contiguous; LDS XOR-swizzled. Also zeroes barriers.
// K2 gather (persistent, XCD-phased, per-XCD barrier): 512 blocks x 256 thr,
//    2/CU co-resident. XCD x = bid&7 owns p in [8x,8x+8), one p per phase; the
//    per-p slab (2.1 MiB) stays in that XCD's 4 MiB L2 (R7 PROVED this:
//    FETCH 483->157 MB). R7's global barrier cost ~70us each (511 pollers
//    hammering one line every 100ns -> coherence-point queueing). Fix:
//    8 independent 64-block barriers, cnt/gen on separate 128B lines,
//    polls every ~3.4us (s_sleep 127). Timeout-bounded, timing-only.
// K3 linear: 128-block GEMM computes relu(Wx+b), folds 8 partials, writes out.

#define NB 4096
#define ND 128
#define NO 256
#define NP 64
#define NG 65
#define PANEL 16384  // 256*64 elements per (i,j) panel
#define FPT_ELEMS ((size_t)NG * NG * PANEL)
#define FPT_BYTES (FPT_ELEMS * 2)                  // 138,444,800 B
#define PART_FLOATS ((size_t)8 * NB * NO)          // 32 MiB
#define NBLK 512
#define BARS 64          // blocks per XCD barrier
#define ESTR 64          // ctrl entry stride in u32 (256B); cnt=+0, gen=+32

typedef float f32x4 __attribute__((ext_vector_type(4)));
union Pack8 { __half h[8]; uint4 v; };

__device__ __forceinline__ int bsearch65(const float* B, float v) {
  int lo = 0, hi = 65;
  while (lo < hi) {
    int m = (lo + hi) >> 1;
    if (B[m] <= v) lo = m + 1; else hi = m;
  }
  int i = lo - 1;
  return i < 0 ? 0 : (i > 63 ? 63 : i);
}

__device__ __forceinline__ void borders_init(float* borders, int t) {
  if (t < 65) {
    float pk = fminf(fmaxf((float)t * (1.0f / 64.0f), 0.0078125f), 0.9921875f);
    borders[t] = 1.41421356237309515f * erfinvf(2.0f * pk - 1.0f);
  }
}

// Per-XCD sense-reversing barrier (64 blocks). Timing-only: bounded spin,
// correctness never depends on it. Low poll rate to avoid coherence-point
// queueing (R7 lesson).
__device__ __forceinline__ void xcd_barrier(unsigned* e) {
  __syncthreads();
  if (threadIdx.x == 0) {
    unsigned* cnt = e;
    unsigned* gen = e + 32;   // separate 128B line
    unsigned g = __hip_atomic_load(gen, __ATOMIC_RELAXED, __HIP_MEMORY_SCOPE_AGENT);
    unsigned a = __hip_atomic_fetch_add(cnt, 1u, __ATOMIC_ACQ_REL,
                                        __HIP_MEMORY_SCOPE_AGENT) + 1u;
    if (a == BARS) {
      __hip_atomic_store(cnt, 0u, __ATOMIC_RELAXED, __HIP_MEMORY_SCOPE_AGENT);
      __hip_atomic_fetch_add(gen, 1u, __ATOMIC_RELEASE, __HIP_MEMORY_SCOPE_AGENT);
    } else if (__hip_atomic_load(gen, __ATOMIC_RELAXED,
                                 __HIP_MEMORY_SCOPE_AGENT) == g) {  // fast path
      for (int it = 0; it < 32; ++it) {    // cap ~110us: timing aid only
        __builtin_amdgcn_s_sleep(127);     // ~3.4us between polls
        if (__hip_atomic_load(gen, __ATOMIC_RELAXED,
                              __HIP_MEMORY_SCOPE_AGENT) != g) break;
      }
    }
  }
  __syncthreads();
}

// ---- K1: transpose fp[panel][o][p] f32 -> fpt[panel][p][o] f16 ----
__global__ __launch_bounds__(256) void lmkan_transpose3(
    const float* __restrict__ src, __half* __restrict__ dst,
    unsigned* __restrict__ ctrl) {
  const int panel = blockIdx.x;
  const int t = threadIdx.x;
  __shared__ __half lds[256 * 72];   // [o][72], p XOR-swizzled inside row

  if (panel == 0) {                  // reset all 8 barrier entries each replay
    ctrl[t] = 0u;                    // 8*64 = 512 u32s, t covers 0..255
    ctrl[t + 256] = 0u;
  }

  const f32x4* s4 = reinterpret_cast<const f32x4*>(src + (size_t)panel * PANEL);
#pragma unroll
  for (int k = 0; k < 16; ++k) {
    int idx4 = t + 256 * k;          // 1KB contiguous per wave
    f32x4 v = __builtin_nontemporal_load(&s4[idx4]);  // read-once
    int o = idx4 >> 4;
    int p0 = (idx4 & 15) * 4;
    int p0s = p0 ^ (((o >> 3) & 15) << 2);
    union { __half2 h2[2]; uint2 u; } pk;
    pk.h2[0] = __floats2half2_rn(v[0], v[1]);
    pk.h2[1] = __floats2half2_rn(v[2], v[3]);
    *reinterpret_cast<uint2*>(&lds[o * 72 + p0s]) = pk.u;
  }
  __syncthreads();

  const int l = t & 63, w = t >> 6;
  const int o0 = (l & 31) * 8;
  const int swz = (l & 15) << 2;
#pragma unroll
  for (int ss = 0; ss < 8; ++ss) {
    int p = ss * 8 + w * 2 + (l >> 5);
    int prow = ((p & ~3) ^ swz) + (p & 3);
    Pack8 pk;
#pragma unroll
    for (int r = 0; r < 8; ++r) pk.h[r] = lds[(o0 + r) * 72 + prow];
    *reinterpret_cast<uint4*>(dst + ((size_t)panel * 64 + p) * NO + o0) = pk.v;
  }
}

__device__ __forceinline__ void fma4h(float acc[4], float w, uint2 v) {
  __half2 h0 = *reinterpret_cast<__half2*>(&v.x);
  __half2 h1 = *reinterpret_cast<__half2*>(&v.y);
  float2 f0 = __half22float2(h0);
  float2 f1 = __half22float2(h1);
  acc[0] = fmaf(w, f0.x, acc[0]);
  acc[1] = fmaf(w, f0.y, acc[1]);
  acc[2] = fmaf(w, f1.x, acc[2]);
  acc[3] = fmaf(w, f1.y, acc[3]);
}

// ---- K2: persistent XCD-phased gather with per-XCD alignment -> partials ----
__global__ __launch_bounds__(256, 2) void lmkan_gather8(
    const float* __restrict__ x, const float* __restrict__ scale,
    const float* __restrict__ biasp, const __half* __restrict__ fpt,
    float* __restrict__ part, unsigned* __restrict__ ctrl) {
  const int xcd = blockIdx.x & 7;    // owns p in [8*xcd, 8*xcd+8)
  const int m   = blockIdx.x >> 3;   // 0..63: b-range [64m, 64m+64)
  const int t = threadIdx.x;         // 0..255
  const int w = t >> 6;              // wave 0..3: b-locals [16w, 16w+16)
  const int l = t & 63;              // lane owns o = 4l..4l+3
  const int loff = 4 * l;
  unsigned* bar = ctrl + xcd * ESTR;

  __shared__ float borders[66];
  __shared__ int jb[64];             // element base of (panel(i,j), p, o=0)
  __shared__ float4 w4[64];          // {w00, w01, w10, w11}

  borders_init(borders, t);
  __syncthreads();

  float acc[16][4] = {};

  for (int ph = 0; ph < 8; ++ph) {
    const int p = 8 * xcd + ph;
    if (t < 64) {
      const int b = m * 64 + t;
      float x1 = x[(size_t)(2 * p) * NB + b]     * scale[2 * p]     + biasp[2 * p];
      float x2 = x[(size_t)(2 * p + 1) * NB + b] * scale[2 * p + 1] + biasp[2 * p + 1];
      const float lo = borders[0];
      const float hi = borders[64] - 1e-6f;
      x1 = fminf(fmaxf(x1, lo), hi);
      x2 = fminf(fmaxf(x2, lo), hi);
      int i = bsearch65(borders, x1);
      int j = bsearch65(borders, x2);
      float t1 = (x1 - borders[i]) / (borders[i + 1] - borders[i]);
      float t2 = (x2 - borders[j]) / (borders[j + 1] - borders[j]);
      jb[t] = ((i * NG + j) * 64 + p) * NO;
      w4[t] = make_float4((1.0f - t1) * (1.0f - t2),  // (i,   j)  : +0
                          (1.0f - t1) * t2,           // (i,   j+1): +PANEL
                          t1 * (1.0f - t2),           // (i+1, j)  : +65*PANEL
                          t1 * t2);                   // (i+1, j+1): +66*PANEL
    }
    __syncthreads();
#pragma unroll
    for (int bb = 0; bb < 16; ++bb) {
      const int bl = w * 16 + bb;
      const float4 wv = w4[bl];
      const __half* q = fpt + jb[bl] + loff;
      uint2 vA = *reinterpret_cast<const uint2*>(q);
      uint2 vB = *reinterpret_cast<const uint2*>(q + PANEL);
      uint2 vC = *reinterpret_cast<const uint2*>(q + 65 * PANEL);
      uint2 vD = *reinterpret_cast<const uint2*>(q + 66 * PANEL);
      fma4h(acc[bb], wv.x, vA);
      fma4h(acc[bb], wv.y, vB);
      fma4h(acc[bb], wv.z, vC);
      fma4h(acc[bb], wv.w, vD);
    }
    if (ph < 7) xcd_barrier(bar);    // keep this XCD's blocks on one slab
  }

  // write partials: part[xcd][b][o], per-XCD contiguous 4 MiB
#pragma unroll
  for (int bb = 0; bb < 16; ++bb) {
    const int b = m * 64 + w * 16 + bb;
    *reinterpret_cast<float4*>(&part[((size_t)xcd * NB + b) * NO + loff]) =
        make_float4(acc[bb][0], acc[bb][1], acc[bb][2], acc[bb][3]);
  }
}

// ---- K3: out = relu(W@x + bias) + wlm * sum_k part ----
__global__ __launch_bounds__(256) void lmkan_linear2(
    const float* __restrict__ x, const float* __restrict__ W,
    const float* __restrict__ bias_l, const int* __restrict__ relu_p,
    const float* __restrict__ wlm_p, const float* __restrict__ part,
    float* __restrict__ out) {
  const int b0 = blockIdx.x * 32;
  const int t = threadIdx.x;          // = output row o
  __shared__ __align__(16) float xs[32 * 132];

#pragma unroll
  for (int k = 0; k < 16; ++k) {
    int idx = t + 256 * k;
    int d = idx >> 5, bb = idx & 31;
    xs[bb * 132 + d] = x[(size_t)d * NB + b0 + bb];
  }
  __syncthreads();

  float acc[32];
#pragma unroll
  for (int bb = 0; bb < 32; ++bb) acc[bb] = 0.0f;

  const float4* W4 = reinterpret_cast<const float4*>(W + (size_t)t * ND);
#pragma unroll 8
  for (int d4 = 0; d4 < 32; ++d4) {
    float4 wv = W4[d4];
#pragma unroll
    for (int bb = 0; bb < 32; ++bb) {
      float4 xv = *reinterpret_cast<const float4*>(&xs[bb * 132 + d4 * 4]);
      acc[bb] = fmaf(wv.x, xv.x, acc[bb]);
      acc[bb] = fmaf(wv.y, xv.y, acc[bb]);
      acc[bb] = fmaf(wv.z, xv.z, acc[bb]);
      acc[bb] = fmaf(wv.w, xv.w, acc[bb]);
    }
  }

  const float bias = bias_l[t];
  const int rl = relu_p[0];
  const float wlm = wlm_p[0];
  float* orow = out + (size_t)t * NB + b0;
#pragma unroll 4
  for (int bb = 0; bb < 32; ++bb) {
    float lmsum = 0.0f;
    const float* pr = part + (size_t)(b0 + bb) * NO + t;  // lanes coalesced
#pragma unroll
    for (int k = 0; k < 8; ++k) lmsum += pr[(size_t)k * NB * NO];
    float v = acc[bb] + bias;
    if (rl) v = fmaxf(v, 0.0f);
    orow[bb] = v + wlm * lmsum;
  }
}

// ---- Fallback: direct fp32 gather, fused linear (exact, slow) ----
__global__ __launch_bounds__(64) void lmkan_gather_direct(
    const float* __restrict__ x, const float* __restrict__ scale,
    const float* __restrict__ biasp, const float* __restrict__ W,
    const float* __restrict__ bias_l, const float* __restrict__ wlm_p,
    const int* __restrict__ relu_p, const float* __restrict__ fp,
    float* __restrict__ out) {
  const int b = blockIdx.x;
  const int t = threadIdx.x;

  __shared__ float borders[66];
  __shared__ __align__(16) float xcol[ND];
  __shared__ int pbase[NP];
  __shared__ float4 pw[NP];

  for (int k = t; k < 65; k += 64) {
    float pk = fminf(fmaxf((float)k * (1.0f / 64.0f), 0.0078125f), 0.9921875f);
    borders[k] = 1.41421356237309515f * erfinvf(2.0f * pk - 1.0f);
  }
  xcol[t]      = x[(size_t)t * NB + b];
  xcol[t + 64] = x[(size_t)(t + 64) * NB + b];
  __syncthreads();

  {
    const int p = t;
    float x1 = xcol[2 * p]     * scale[2 * p]     + biasp[2 * p];
    float x2 = xcol[2 * p + 1] * scale[2 * p + 1] + biasp[2 * p + 1];
    const float lo = borders[0];
    const float hi = borders[64] - 1e-6f;
    x1 = fminf(fmaxf(x1, lo), hi);
    x2 = fminf(fmaxf(x2, lo), hi);
    int i = bsearch65(borders, x1);
    int j = bsearch65(borders, x2);
    float t1 = (x1 - borders[i]) / (borders[i + 1] - borders[i]);
    float t2 = (x2 - borders[j]) / (borders[j + 1] - borders[j]);
    pbase[p] = i * NG + j;
    pw[p] = make_float4((1.0f - t1) * (1.0f - t2), t1 * (1.0f - t2),
                        (1.0f - t1) * t2, t1 * t2);
  }
  __syncthreads();

  float acc[4] = {0, 0, 0, 0};
  for (int p = 0; p < NP; ++p) {
    int base = pbase[p];
    float4 wv = pw[p];
#pragma unroll
    for (int k = 0; k < 4; ++k) {
      size_t r = ((size_t)base * NO + (4 * t + k)) * NP + p;
      acc[k] += wv.x * fp[r] + wv.y * fp[r + 65 * PANEL] +
                wv.z * fp[r + PANEL] + wv.w * fp[r + 66 * PANEL];
    }
  }

  const float wlm = wlm_p[0];
  const int rl = relu_p[0];
  const float4* xc4 = reinterpret_cast<const float4*>(xcol);
#pragma unroll
  for (int k = 0; k < 4; ++k) {
    const int o = 4 * t + k;
    const float4* wr = reinterpret_cast<const float4*>(W + (size_t)o * ND);
    float s = 0.0f;
#pragma unroll 8
    for (int d4 = 0; d4 < ND / 4; ++d4) {
      float4 wv = wr[d4];
      float4 xv = xc4[d4];
      s = fmaf(wv.x, xv.x, s);
      s = fmaf(wv.y, xv.y, s);
      s = fmaf(wv.z, xv.z, s);
      s = fmaf(wv.w, xv.w, s);
    }
    s += bias_l[o];
    if (rl) s = fmaxf(s, 0.0f);
    out[(size_t)o * NB + b] = s + wlm * acc[k];
  }
}

extern "C" void kernel_launch(void* const* d_in, const int* in_sizes, int n_in,
                              void* d_out, int out_size, void* d_ws, size_t ws_size,
                              hipStream_t stream) {
  const float* x     = reinterpret_cast<const float*>(d_in[0]);
  const float* wlm   = reinterpret_cast<const float*>(d_in[1]);
  const int*   relu  = reinterpret_cast<const int*>(d_in[2]);
  const float* fp    = reinterpret_cast<const float*>(d_in[3]);
  const float* scale = reinterpret_cast<const float*>(d_in[4]);
  const float* biasp = reinterpret_cast<const float*>(d_in[5]);
  const float* W     = reinterpret_cast<const float*>(d_in[6]);
  const float* bl    = reinterpret_cast<const float*>(d_in[7]);
  float* out = reinterpret_cast<float*>(d_out);

  const size_t need = FPT_BYTES + PART_FLOATS * sizeof(float) + 2048;
  if (ws_size >= need) {
    char* base = reinterpret_cast<char*>(d_ws);
    __half* fpt = reinterpret_cast<__half*>(base);
    float* part = reinterpret_cast<float*>(base + FPT_BYTES);
    unsigned* ctrl = reinterpret_cast<unsigned*>(
        base + FPT_BYTES + PART_FLOATS * sizeof(float));
    lmkan_transpose3<<<NG * NG, 256, 0, stream>>>(fp, fpt, ctrl);
    lmkan_gather8<<<NBLK, 256, 0, stream>>>(x, scale, biasp, fpt, part, ctrl);
    lmkan_linear2<<<NB / 32, 256, 0, stream>>>(x, W, bl, relu, wlm, part, out);
  } else {
    lmkan_gather_direct<<<NB, 64, 0, stream>>>(x, scale, biasp, W, bl, wlm, relu, fp, out);
  }
}

// Round 9
// 206.692 us; speedup vs baseline: 3.1742x; 1.4744x over previous
//
#include <hip/hip_runtime.h>
#include <hip/hip_fp16.h>

// LMKAN_2D: out(O=256,B=4096) = relu(W(256x128)@x(128x4096) + bias_l)
//           + w_lm * sum_p bilinear4(fp[i,j,:,p])
// K1 transpose: fp[i][j][o][p] f32 -> fpt[i][j][p][o] f16 (132 MiB). Both
//    global sides 1KB/wave contiguous; LDS XOR-swizzled. Zeroes barrier ctrl.
// K2 gather (persistent, XCD-phased): 512 blocks x 256 thr, 2/CU co-resident.
//    XCD x = bid&7 owns p in [8x,8x+8), one p per phase; per-p slab (2.1 MiB)
//    stays in that XCD's L2 (R7/R8 PROVED: FETCH 483->157 MB). R8 lesson:
//    ACQ_REL agent-scope barrier atomics emit L2-INVALIDATES (multi-XCD
//    coherence) -> flushed the slab every phase -> reads fell to L3 scatter
//    rate (~2.8 TB/s = the 180us overhead). Fix: barrier is timing-only ->
//    ALL-RELAXED atomics (no invalidate; agent-scope still bypasses caches
//    for the atomic access itself), per-phase counters (no reset/mixing),
//    ~1.7us polls, timeout-bounded. Correctness NEVER depends on barrier.
// K3 linear: 128-block GEMM computes relu(Wx+b), folds 8 partials, writes out.

#define NB 4096
#define ND 128
#define NO 256
#define NP 64
#define NG 65
#define PANEL 16384  // 256*64 elements per (i,j) panel
#define FPT_ELEMS ((size_t)NG * NG * PANEL)
#define FPT_BYTES (FPT_ELEMS * 2)                  // 138,444,800 B
#define PART_FLOATS ((size_t)8 * NB * NO)          // 32 MiB
#define NBLK 512
#define BARS 64          // blocks per XCD
#define CTRL_U32 4096    // 8 xcd * 8 ph * 64-u32 stride (256B lines)

typedef float f32x4 __attribute__((ext_vector_type(4)));
union Pack8 { __half h[8]; uint4 v; };

__device__ __forceinline__ int bsearch65(const float* B, float v) {
  int lo = 0, hi = 65;
  while (lo < hi) {
    int m = (lo + hi) >> 1;
    if (B[m] <= v) lo = m + 1; else hi = m;
  }
  int i = lo - 1;
  return i < 0 ? 0 : (i > 63 ? 63 : i);
}

__device__ __forceinline__ void borders_init(float* borders, int t) {
  if (t < 65) {
    float pk = fminf(fmaxf((float)t * (1.0f / 64.0f), 0.0078125f), 0.9921875f);
    borders[t] = 1.41421356237309515f * erfinvf(2.0f * pk - 1.0f);
  }
}

// Per-XCD, per-phase arrival counter. RELAXED-only (no L2 invalidate!),
// no reset (one counter per phase), bounded spin: timing aid only.
__device__ __forceinline__ void xcd_barrier(unsigned* ctrl, int xcd, int ph) {
  __syncthreads();
  if (threadIdx.x == 0) {
    unsigned* c = ctrl + (xcd * 8 + ph) * 64;   // own 256B line per (xcd,ph)
    __hip_atomic_fetch_add(c, 1u, __ATOMIC_RELAXED, __HIP_MEMORY_SCOPE_AGENT);
    for (int it = 0; it < 24; ++it) {           // cap ~40us: timing aid only
      if (__hip_atomic_load(c, __ATOMIC_RELAXED,
                            __HIP_MEMORY_SCOPE_AGENT) >= BARS) break;
      __builtin_amdgcn_s_sleep(64);             // ~1.7us between polls
    }
  }
  __syncthreads();
}

// ---- K1: transpose fp[panel][o][p] f32 -> fpt[panel][p][o] f16 ----
__global__ __launch_bounds__(256) void lmkan_transpose3(
    const float* __restrict__ src, __half* __restrict__ dst,
    unsigned* __restrict__ ctrl) {
  const int panel = blockIdx.x;
  const int t = threadIdx.x;
  __shared__ __half lds[256 * 72];   // [o][72], p XOR-swizzled inside row

  if (panel == 0) {                  // reset all phase counters each replay
#pragma unroll
    for (int k = 0; k < 16; ++k) ctrl[t + 256 * k] = 0u;
  }

  const f32x4* s4 = reinterpret_cast<const f32x4*>(src + (size_t)panel * PANEL);
#pragma unroll
  for (int k = 0; k < 16; ++k) {
    int idx4 = t + 256 * k;          // 1KB contiguous per wave
    f32x4 v = __builtin_nontemporal_load(&s4[idx4]);  // read-once
    int o = idx4 >> 4;
    int p0 = (idx4 & 15) * 4;
    int p0s = p0 ^ (((o >> 3) & 15) << 2);
    union { __half2 h2[2]; uint2 u; } pk;
    pk.h2[0] = __floats2half2_rn(v[0], v[1]);
    pk.h2[1] = __floats2half2_rn(v[2], v[3]);
    *reinterpret_cast<uint2*>(&lds[o * 72 + p0s]) = pk.u;
  }
  __syncthreads();

  const int l = t & 63, w = t >> 6;
  const int o0 = (l & 31) * 8;
  const int swz = (l & 15) << 2;
#pragma unroll
  for (int ss = 0; ss < 8; ++ss) {
    int p = ss * 8 + w * 2 + (l >> 5);
    int prow = ((p & ~3) ^ swz) + (p & 3);
    Pack8 pk;
#pragma unroll
    for (int r = 0; r < 8; ++r) pk.h[r] = lds[(o0 + r) * 72 + prow];
    *reinterpret_cast<uint4*>(dst + ((size_t)panel * 64 + p) * NO + o0) = pk.v;
  }
}

__device__ __forceinline__ void fma4h(float acc[4], float w, uint2 v) {
  __half2 h0 = *reinterpret_cast<__half2*>(&v.x);
  __half2 h1 = *reinterpret_cast<__half2*>(&v.y);
  float2 f0 = __half22float2(h0);
  float2 f1 = __half22float2(h1);
  acc[0] = fmaf(w, f0.x, acc[0]);
  acc[1] = fmaf(w, f0.y, acc[1]);
  acc[2] = fmaf(w, f1.x, acc[2]);
  acc[3] = fmaf(w, f1.y, acc[3]);
}

// ---- K2: persistent XCD-phased gather with aligned phases -> partials ----
__global__ __launch_bounds__(256, 2) void lmkan_gather9(
    const float* __restrict__ x, const float* __restrict__ scale,
    const float* __restrict__ biasp, const __half* __restrict__ fpt,
    float* __restrict__ part, unsigned* __restrict__ ctrl) {
  const int xcd = blockIdx.x & 7;    // owns p in [8*xcd, 8*xcd+8)
  const int m   = blockIdx.x >> 3;   // 0..63: b-range [64m, 64m+64)
  const int t = threadIdx.x;         // 0..255
  const int w = t >> 6;              // wave 0..3: b-locals [16w, 16w+16)
  const int l = t & 63;              // lane owns o = 4l..4l+3
  const int loff = 4 * l;

  __shared__ float borders[66];
  __shared__ int jb[64];             // element base of (panel(i,j), p, o=0)
  __shared__ float4 w4[64];          // {w00, w01, w10, w11}

  borders_init(borders, t);
  __syncthreads();

  float acc[16][4] = {};

  for (int ph = 0; ph < 8; ++ph) {
    const int p = 8 * xcd + ph;
    if (t < 64) {
      const int b = m * 64 + t;
      float x1 = x[(size_t)(2 * p) * NB + b]     * scale[2 * p]     + biasp[2 * p];
      float x2 = x[(size_t)(2 * p + 1) * NB + b] * scale[2 * p + 1] + biasp[2 * p + 1];
      const float lo = borders[0];
      const float hi = borders[64] - 1e-6f;
      x1 = fminf(fmaxf(x1, lo), hi);
      x2 = fminf(fmaxf(x2, lo), hi);
      int i = bsearch65(borders, x1);
      int j = bsearch65(borders, x2);
      float t1 = (x1 - borders[i]) / (borders[i + 1] - borders[i]);
      float t2 = (x2 - borders[j]) / (borders[j + 1] - borders[j]);
      jb[t] = ((i * NG + j) * 64 + p) * NO;
      w4[t] = make_float4((1.0f - t1) * (1.0f - t2),  // (i,   j)  : +0
                          (1.0f - t1) * t2,           // (i,   j+1): +PANEL
                          t1 * (1.0f - t2),           // (i+1, j)  : +65*PANEL
                          t1 * t2);                   // (i+1, j+1): +66*PANEL
    }
    __syncthreads();
#pragma unroll
    for (int bb = 0; bb < 16; ++bb) {
      const int bl = w * 16 + bb;
      const float4 wv = w4[bl];
      const __half* q = fpt + jb[bl] + loff;
      uint2 vA = *reinterpret_cast<const uint2*>(q);
      uint2 vB = *reinterpret_cast<const uint2*>(q + PANEL);
      uint2 vC = *reinterpret_cast<const uint2*>(q + 65 * PANEL);
      uint2 vD = *reinterpret_cast<const uint2*>(q + 66 * PANEL);
      fma4h(acc[bb], wv.x, vA);
      fma4h(acc[bb], wv.y, vB);
      fma4h(acc[bb], wv.z, vC);
      fma4h(acc[bb], wv.w, vD);
    }
    if (ph < 7) xcd_barrier(ctrl, xcd, ph);  // keep this XCD on one slab
  }

  // write partials: part[xcd][b][o], per-XCD contiguous 4 MiB
#pragma unroll
  for (int bb = 0; bb < 16; ++bb) {
    const int b = m * 64 + w * 16 + bb;
    *reinterpret_cast<float4*>(&part[((size_t)xcd * NB + b) * NO + loff]) =
        make_float4(acc[bb][0], acc[bb][1], acc[bb][2], acc[bb][3]);
  }
}

// ---- K3: out = relu(W@x + bias) + wlm * sum_k part ----
__global__ __launch_bounds__(256) void lmkan_linear2(
    const float* __restrict__ x, const float* __restrict__ W,
    const float* __restrict__ bias_l, const int* __restrict__ relu_p,
    const float* __restrict__ wlm_p, const float* __restrict__ part,
    float* __restrict__ out) {
  const int b0 = blockIdx.x * 32;
  const int t = threadIdx.x;          // = output row o
  __shared__ __align__(16) float xs[32 * 132];

#pragma unroll
  for (int k = 0; k < 16; ++k) {
    int idx = t + 256 * k;
    int d = idx >> 5, bb = idx & 31;
    xs[bb * 132 + d] = x[(size_t)d * NB + b0 + bb];
  }
  __syncthreads();

  float acc[32];
#pragma unroll
  for (int bb = 0; bb < 32; ++bb) acc[bb] = 0.0f;

  const float4* W4 = reinterpret_cast<const float4*>(W + (size_t)t * ND);
#pragma unroll 8
  for (int d4 = 0; d4 < 32; ++d4) {
    float4 wv = W4[d4];
#pragma unroll
    for (int bb = 0; bb < 32; ++bb) {
      float4 xv = *reinterpret_cast<const float4*>(&xs[bb * 132 + d4 * 4]);
      acc[bb] = fmaf(wv.x, xv.x, acc[bb]);
      acc[bb] = fmaf(wv.y, xv.y, acc[bb]);
      acc[bb] = fmaf(wv.z, xv.z, acc[bb]);
      acc[bb] = fmaf(wv.w, xv.w, acc[bb]);
    }
  }

  const float bias = bias_l[t];
  const int rl = relu_p[0];
  const float wlm = wlm_p[0];
  float* orow = out + (size_t)t * NB + b0;
#pragma unroll 4
  for (int bb = 0; bb < 32; ++bb) {
    float lmsum = 0.0f;
    const float* pr = part + (size_t)(b0 + bb) * NO + t;  // lanes coalesced
#pragma unroll
    for (int k = 0; k < 8; ++k) lmsum += pr[(size_t)k * NB * NO];
    float v = acc[bb] + bias;
    if (rl) v = fmaxf(v, 0.0f);
    orow[bb] = v + wlm * lmsum;
  }
}

// ---- Fallback: direct fp32 gather, fused linear (exact, slow) ----
__global__ __launch_bounds__(64) void lmkan_gather_direct(
    const float* __restrict__ x, const float* __restrict__ scale,
    const float* __restrict__ biasp, const float* __restrict__ W,
    const float* __restrict__ bias_l, const float* __restrict__ wlm_p,
    const int* __restrict__ relu_p, const float* __restrict__ fp,
    float* __restrict__ out) {
  const int b = blockIdx.x;
  const int t = threadIdx.x;

  __shared__ float borders[66];
  __shared__ __align__(16) float xcol[ND];
  __shared__ int pbase[NP];
  __shared__ float4 pw[NP];

  for (int k = t; k < 65; k += 64) {
    float pk = fminf(fmaxf((float)k * (1.0f / 64.0f), 0.0078125f), 0.9921875f);
    borders[k] = 1.41421356237309515f * erfinvf(2.0f * pk - 1.0f);
  }
  xcol[t]      = x[(size_t)t * NB + b];
  xcol[t + 64] = x[(size_t)(t + 64) * NB + b];
  __syncthreads();

  {
    const int p = t;
    float x1 = xcol[2 * p]     * scale[2 * p]     + biasp[2 * p];
    float x2 = xcol[2 * p + 1] * scale[2 * p + 1] + biasp[2 * p + 1];
    const float lo = borders[0];
    const float hi = borders[64] - 1e-6f;
    x1 = fminf(fmaxf(x1, lo), hi);
    x2 = fminf(fmaxf(x2, lo), hi);
    int i = bsearch65(borders, x1);
    int j = bsearch65(borders, x2);
    float t1 = (x1 - borders[i]) / (borders[i + 1] - borders[i]);
    float t2 = (x2 - borders[j]) / (borders[j + 1] - borders[j]);
    pbase[p] = i * NG + j;
    pw[p] = make_float4((1.0f - t1) * (1.0f - t2), t1 * (1.0f - t2),
                        (1.0f - t1) * t2, t1 * t2);
  }
  __syncthreads();

  float acc[4] = {0, 0, 0, 0};
  for (int p = 0; p < NP; ++p) {
    int base = pbase[p];
    float4 wv = pw[p];
#pragma unroll
    for (int k = 0; k < 4; ++k) {
      size_t r = ((size_t)base * NO + (4 * t + k)) * NP + p;
      acc[k] += wv.x * fp[r] + wv.y * fp[r + 65 * PANEL] +
                wv.z * fp[r + PANEL] + wv.w * fp[r + 66 * PANEL];
    }
  }

  const float wlm = wlm_p[0];
  const int rl = relu_p[0];
  const float4* xc4 = reinterpret_cast<const float4*>(xcol);
#pragma unroll
  for (int k = 0; k < 4; ++k) {
    const int o = 4 * t + k;
    const float4* wr = reinterpret_cast<const float4*>(W + (size_t)o * ND);
    float s = 0.0f;
#pragma unroll 8
    for (int d4 = 0; d4 < ND / 4; ++d4) {
      float4 wv = wr[d4];
      float4 xv = xc4[d4];
      s = fmaf(wv.x, xv.x, s);
      s = fmaf(wv.y, xv.y, s);
      s = fmaf(wv.z, xv.z, s);
      s = fmaf(wv.w, xv.w, s);
    }
    s += bias_l[o];
    if (rl) s = fmaxf(s, 0.0f);
    out[(size_t)o * NB + b] = s + wlm * acc[k];
  }
}

extern "C" void kernel_launch(void* const* d_in, const int* in_sizes, int n_in,
                              void* d_out, int out_size, void* d_ws, size_t ws_size,
                              hipStream_t stream) {
  const float* x     = reinterpret_cast<const float*>(d_in[0]);
  const float* wlm   = reinterpret_cast<const float*>(d_in[1]);
  const int*   relu  = reinterpret_cast<const int*>(d_in[2]);
  const float* fp    = reinterpret_cast<const float*>(d_in[3]);
  const float* scale = reinterpret_cast<const float*>(d_in[4]);
  const float* biasp = reinterpret_cast<const float*>(d_in[5]);
  const float* W     = reinterpret_cast<const float*>(d_in[6]);
  const float* bl    = reinterpret_cast<const float*>(d_in[7]);
  float* out = reinterpret_cast<float*>(d_out);

  const size_t need = FPT_BYTES + PART_FLOATS * sizeof(float)
                      + CTRL_U32 * sizeof(unsigned);
  if (ws_size >= need) {
    char* base = reinterpret_cast<char*>(d_ws);
    __half* fpt = reinterpret_cast<__half*>(base);
    float* part = reinterpret_cast<float*>(base + FPT_BYTES);
    unsigned* ctrl = reinterpret_cast<unsigned*>(
        base + FPT_BYTES + PART_FLOATS * sizeof(float));
    lmkan_transpose3<<<NG * NG, 256, 0, stream>>>(fp, fpt, ctrl);
    lmkan_gather9<<<NBLK, 256, 0, stream>>>(x, scale, biasp, fpt, part, ctrl);
    lmkan_linear2<<<NB / 32, 256, 0, stream>>>(x, W, bl, relu, wlm, part, out);
  } else {
    lmkan_gather_direct<<<NB, 64, 0, stream>>>(x, scale, biasp, W, bl, wlm, relu, fp, out);
  }
}